// Round 3
// baseline (147.770 us; speedup 1.0000x reference)
//
#include <hip/hip_runtime.h>

#define NHEAD 32
#define LSEQ  2048
#define DIM   64
#define QBLK  64
#define KBLK  64
#define NTILE (LSEQ / KBLK)

typedef float  f32x4  __attribute__((ext_vector_type(4)));
typedef __bf16 bf16x8 __attribute__((ext_vector_type(8)));
typedef unsigned short u16;

__device__ __forceinline__ u16 f2bf(float f) {
    return __builtin_bit_cast(u16, (__bf16)f);   // HW RNE convert
}
__device__ __forceinline__ void st4bf(u16* p, float4 v) {
    union { u16 h[4]; uint2 q; } pk;
    pk.h[0] = f2bf(v.x); pk.h[1] = f2bf(v.y);
    pk.h[2] = f2bf(v.z); pk.h[3] = f2bf(v.w);
    *(uint2*)p = pk.q;
}
// combine two 8B LDS reads into one bf16x8 fragment (slots 0-3 = a, 4-7 = b)
__device__ __forceinline__ bf16x8 comb64(const u16* a, const u16* b) {
    union { uint2 q[2]; bf16x8 v; } u;
    u.q[0] = *(const uint2*)a;
    u.q[1] = *(const uint2*)b;
    return u.v;
}

// 0.125 (1/sqrt(64)) * log2(e): softmax computed in exp2 domain
#define QSCALE 0.18033688011112042f
// defer-max threshold (exp2 domain): p bounded by 2^8
#define RESCALE_THR 8.0f

__launch_bounds__(256, 4)
__global__ void attn_fused_kernel(const float* __restrict__ Q,
                                  const float* __restrict__ K,
                                  const float* __restrict__ V,
                                  const float* __restrict__ Msk,
                                  float* __restrict__ out,
                                  float* __restrict__ loss)
{
    // double-buffered. K pitch 72 hw (16B-aligned b128 rows, uniform banks);
    // V pitch 68 hw: b64 write at [l][4w+16i] -> bank (2l+c)%32 -> 4 lanes/bank-pair
    // = 4-cy minimum (conflict-free), read comb64 unchanged (measured clean).
    __shared__ __align__(16) u16 lds_k[2][64][72];   // K tile  [k_row][c]   (bf16)
    __shared__ __align__(16) u16 lds_v[2][64][68];   // V^T     [d][k_row]   (bf16)

    const int t  = threadIdx.x;
    // bijective XCD-chunked swizzle: 1024 blocks, 8 XCDs, 128-block chunks
    const int wg   = ((int)blockIdx.x & 7) * 128 + ((int)blockIdx.x >> 3);
    const int head = wg >> 5;
    const int qb   = wg & 31;
    const int qbase = qb * QBLK;
    const int w  = t >> 6;
    const int l  = t & 63;
    const int lr = l & 15;   // A-row / B-col index
    const int lq = l >> 4;   // k-group / D-row-group

    const size_t hoff = (size_t)head * LSEQ * DIM;
    const int qg = qbase + 16 * w + lr;          // this lane's q row (B-col side)

    // ---- Q fragments for q row = qg, scale folded in (slots c = 32s + 8lq + j) ----
    bf16x8 qf[2];
#pragma unroll
    for (int s = 0; s < 2; ++s) {
        const float* src = Q + hoff + (size_t)qg * DIM + 32 * s + 8 * lq;
        float4 a = *(const float4*)(src);
        float4 b = *(const float4*)(src + 4);
        union { u16 h[8]; bf16x8 v; } u;
        u.h[0] = f2bf(a.x * QSCALE); u.h[1] = f2bf(a.y * QSCALE);
        u.h[2] = f2bf(a.z * QSCALE); u.h[3] = f2bf(a.w * QSCALE);
        u.h[4] = f2bf(b.x * QSCALE); u.h[5] = f2bf(b.y * QSCALE);
        u.h[6] = f2bf(b.z * QSCALE); u.h[7] = f2bf(b.w * QSCALE);
        qf[s] = u.v;
    }

    f32x4 acc[4];                 // O^T fragments: col=q(=lr), row d = 16dt+4lq+r
#pragma unroll
    for (int dt = 0; dt < 4; ++dt) acc[dt] = (f32x4){0.f, 0.f, 0.f, 0.f};
    float mrun = -1e30f, lrun = 0.f, la2 = 0.f, lam = 0.f;

    // ---- register staging (prefetch for tile kb+1 issued AFTER the barrier
    //      of tile kb, consumed at top of tile kb+1: latency hides under the
    //      full compute phase; nothing in flight when syncthreads drains vmcnt) ----
    const float* Kg = K + hoff;
    const float* Vg = V + hoff + l;     // V: lane owns d = l
    const int krow0 = t >> 4;           // K stage row (+16i)
    const int kcol  = (t & 15) * 4;     // K stage col

    float4 kr[4];                 // K: 4 rows of float4 (4 d at one k-row)
    float  vr[16];                // V: k = 4w+16i+j at d = l (coalesced 256B loads)

    auto issue = [&](int kb) {
        const float* kp = Kg + (size_t)(kb * KBLK) * DIM;
        const float* vp = Vg + (size_t)(kb * KBLK) * DIM;
#pragma unroll
        for (int i = 0; i < 4; ++i)
            kr[i] = *(const float4*)(kp + (krow0 + 16 * i) * DIM + kcol);
#pragma unroll
        for (int i = 0; i < 4; ++i) {
#pragma unroll
            for (int j = 0; j < 4; ++j)
                vr[4 * i + j] = vp[(4 * w + 16 * i + j) * DIM];
        }
    };

    issue(0);
    int cur = 0;

    for (int kb = 0; kb < NTILE; ++kb) {
        // ---- write staged tile kb (regs -> LDS[cur], fp32 -> bf16) ----
#pragma unroll
        for (int i = 0; i < 4; ++i)
            st4bf(&lds_k[cur][krow0 + 16 * i][kcol], kr[i]);
#pragma unroll
        for (int i = 0; i < 4; ++i) {
            float4 vv;
            vv.x = vr[4 * i + 0]; vv.y = vr[4 * i + 1];
            vv.z = vr[4 * i + 2]; vv.w = vr[4 * i + 3];
            st4bf(&lds_v[cur][l][4 * w + 16 * i], vv);
        }
        __syncthreads();   // single barrier per tile (double-buffered LDS)

        // ---- mask straight to registers (issued before prefetch so its wait
        //      doesn't drain the prefetch queue; consumed after S) ----
        f32x4 mreg[4];
        {
            const float* mp_ = Msk + (size_t)qg * LSEQ + kb * KBLK + 4 * lq;
#pragma unroll
            for (int m = 0; m < 4; ++m)
                mreg[m] = *(const f32x4*)(mp_ + 16 * m);
        }

        if (kb + 1 < NTILE) issue(kb + 1);   // prefetch next tile

        // ---- S^T = K * Q^T : D col=q(=lr), row k = 16m + 4lq + r ----
        f32x4 S[4];
#pragma unroll
        for (int m = 0; m < 4; ++m) {
            bf16x8 kf0 = *(const bf16x8*)&lds_k[cur][16 * m + lr][8 * lq];
            bf16x8 kf1 = *(const bf16x8*)&lds_k[cur][16 * m + lr][32 + 8 * lq];
            f32x4 z = (f32x4){0.f, 0.f, 0.f, 0.f};
            z = __builtin_amdgcn_mfma_f32_16x16x32_bf16(kf0, qf[0], z, 0, 0, 0);
            z = __builtin_amdgcn_mfma_f32_16x16x32_bf16(kf1, qf[1], z, 0, 0, 0);
            S[m] = z;
        }

        // ---- in-lane online softmax with defer-max (T13) ----
        float tm = fmaxf(fmaxf(fmaxf(S[0][0], S[0][1]), fmaxf(S[0][2], S[0][3])),
                         fmaxf(fmaxf(S[1][0], S[1][1]), fmaxf(S[1][2], S[1][3])));
        tm = fmaxf(tm, fmaxf(fmaxf(fmaxf(S[2][0], S[2][1]), fmaxf(S[2][2], S[2][3])),
                             fmaxf(fmaxf(S[3][0], S[3][1]), fmaxf(S[3][2], S[3][3]))));
        tm = fmaxf(tm, __shfl_xor(tm, 16));
        tm = fmaxf(tm, __shfl_xor(tm, 32));
        if (!__all(tm - mrun <= RESCALE_THR)) {      // wave-uniform branch
            const float mn = fmaxf(mrun, tm);
            const float al = __builtin_amdgcn_exp2f(mrun - mn);
            mrun = mn;
            lrun *= al; la2 *= al * al; lam *= al;
#pragma unroll
            for (int dt = 0; dt < 4; ++dt) acc[dt] *= al;
        }

        float psum = 0.f, pp2 = 0.f, ppm = 0.f;
        u16 pb[16];
#pragma unroll
        for (int m = 0; m < 4; ++m) {
#pragma unroll
            for (int r = 0; r < 4; ++r) {
                float p = __builtin_amdgcn_exp2f(S[m][r] - mrun);
                psum += p;
                pp2  += p * p;
                ppm  += p * mreg[m][r];
                pb[4 * m + r] = f2bf(p);
            }
        }
        lrun += psum; la2 += pp2; lam += ppm;

        // ---- O^T += V^T * P : A=V^T (row=d), B=P packed with matching k-slots ----
        bf16x8 pf[2];
#pragma unroll
        for (int mp = 0; mp < 2; ++mp) {
            union { u16 h[8]; bf16x8 v; } u;
#pragma unroll
            for (int j = 0; j < 4; ++j) { u.h[j] = pb[8 * mp + j]; u.h[4 + j] = pb[8 * mp + 4 + j]; }
            pf[mp] = u.v;
        }
#pragma unroll
        for (int dt = 0; dt < 4; ++dt) {
#pragma unroll
            for (int mp = 0; mp < 2; ++mp) {
                bf16x8 vf = comb64(&lds_v[cur][16 * dt + lr][32 * mp + 4 * lq],
                                   &lds_v[cur][16 * dt + lr][32 * mp + 16 + 4 * lq]);
                acc[dt] = __builtin_amdgcn_mfma_f32_16x16x32_bf16(vf, pf[mp], acc[dt], 0, 0, 0);
            }
        }
        cur ^= 1;
    }

    // ---- reduce per-lane row partials across the 4 k-groups (lanes xor 16,32) ----
#pragma unroll
    for (int off = 16; off <= 32; off <<= 1) {
        lrun += __shfl_xor(lrun, off);
        la2  += __shfl_xor(la2,  off);
        lam  += __shfl_xor(lam,  off);
    }

    const float inv = 1.0f / lrun;

    // ---- context write: float4 of 4 consecutive d per acc tile ----
#pragma unroll
    for (int dt = 0; dt < 4; ++dt) {
        float4 o;
        o.x = acc[dt][0] * inv; o.y = acc[dt][1] * inv;
        o.z = acc[dt][2] * inv; o.w = acc[dt][3] * inv;
        *(float4*)(out + hoff + (size_t)qg * DIM + 16 * dt + 4 * lq) = o;
    }

    // ---- loss partial: one value per q row (keep lq==0 lanes), wave-reduce, one atomic ----
    float part = la2 * inv * inv - 2.0f * lam * inv;
    part = (l < 16) ? part : 0.f;
#pragma unroll
    for (int off = 1; off <= 8; off <<= 1) part += __shfl_xor(part, off);
    if (l == 0) atomicAdd(loss, part);
}

// loss += 32 * sum(mask^2), fp32 (dominant loss term, kept near-exact)
__global__ void masksq_kernel(const float* __restrict__ Msk, float* __restrict__ loss)
{
    __shared__ float red[4];
    float s = 0.f;
    const size_t n4 = (size_t)LSEQ * LSEQ / 4;
    for (size_t i = (size_t)blockIdx.x * blockDim.x + threadIdx.x; i < n4;
         i += (size_t)gridDim.x * blockDim.x) {
        float4 v = ((const float4*)Msk)[i];
        s += v.x * v.x + v.y * v.y + v.z * v.z + v.w * v.w;
    }
#pragma unroll
    for (int off = 1; off <= 32; off <<= 1) s += __shfl_xor(s, off);
    if ((threadIdx.x & 63) == 0) red[threadIdx.x >> 6] = s;
    __syncthreads();
    if (threadIdx.x == 0) {
        float tot = red[0] + red[1] + red[2] + red[3];
        atomicAdd(loss, 32.0f * tot);
    }
}

extern "C" void kernel_launch(void* const* d_in, const int* in_sizes, int n_in,
                              void* d_out, int out_size, void* d_ws, size_t ws_size,
                              hipStream_t stream)
{
    const float* Q   = (const float*)d_in[0];
    const float* K   = (const float*)d_in[1];
    const float* V   = (const float*)d_in[2];
    const float* Msk = (const float*)d_in[3];
    float* out  = (float*)d_out;
    float* loss = out + (size_t)NHEAD * LSEQ * DIM;  // element 4194304

    hipMemsetAsync(loss, 0, sizeof(float), stream);
    masksq_kernel<<<256, 256, 0, stream>>>(Msk, loss);
    attn_fused_kernel<<<NHEAD * (LSEQ / QBLK), 256, 0, stream>>>(Q, K, V, Msk, out, loss);
}

// Round 4
// 147.104 us; speedup vs baseline: 1.0045x; 1.0045x over previous
//
#include <hip/hip_runtime.h>

#define NHEAD 32
#define LSEQ  2048
#define DIM   64
#define QBLK  64
#define KBLK  64
#define NTILE (LSEQ / KBLK)

typedef float  f32x4  __attribute__((ext_vector_type(4)));
typedef __bf16 bf16x8 __attribute__((ext_vector_type(8)));
typedef unsigned short u16;

__device__ __forceinline__ u16 f2bf(float f) {
    return __builtin_bit_cast(u16, (__bf16)f);   // HW RNE convert
}
__device__ __forceinline__ void st4bf(u16* p, float4 v) {
    union { u16 h[4]; uint2 q; } pk;
    pk.h[0] = f2bf(v.x); pk.h[1] = f2bf(v.y);
    pk.h[2] = f2bf(v.z); pk.h[3] = f2bf(v.w);
    *(uint2*)p = pk.q;
}
__device__ __forceinline__ bf16x8 comb64(const u16* a, const u16* b) {
    union { uint2 q[2]; bf16x8 v; } u;
    u.q[0] = *(const uint2*)a;
    u.q[1] = *(const uint2*)b;
    return u.v;
}

// async global->LDS, 16B per lane (HW: wave-uniform LDS base + lane*16)
__device__ __forceinline__ void gl_lds16(const u16* g, u16* l) {
    __builtin_amdgcn_global_load_lds(
        (const __attribute__((address_space(1))) void*)g,
        (__attribute__((address_space(3))) void*)l, 16, 0, 0);
}

// drain own async stages + barrier. No lgkm drain needed: the main loop has
// zero ds_writes, and all ds_reads were lgkm-waited before their MFMA use.
#define TILE_SYNC() asm volatile("s_waitcnt vmcnt(0)\n\ts_barrier" ::: "memory")

// 0.125 (1/sqrt(64)) * log2(e): softmax computed in exp2 domain
#define QSCALE 0.18033688011112042f
#define RESCALE_THR 8.0f

// ============================================================================
// Pre-pass: K -> bf16 tiles, V -> V^T bf16 tiles, in gload_lds-linear +
// XOR-swizzled layout. One block per (head, k-tile).
// K tile image: row r (128B), 16B chunk q holds d = 8*(q^(r&7)) + 0..7.
// V^T image: row d (128B), chunk q = two 4-k halves s=0,1 with
//   c_log = q^(d&7), mp = c_log>>2, lq = c_log&3, k0 = 4*(8*mp+4*s+lq).
// ============================================================================
__global__ void prepack_kernel(const float* __restrict__ K,
                               const float* __restrict__ V,
                               u16* __restrict__ wsK, u16* __restrict__ wsV)
{
    __shared__ float sv[64][65];
    const int b = blockIdx.x;          // head*NTILE + kb
    const int head = b >> 5, kb = b & 31;
    const int t = threadIdx.x;
    const size_t hoff = (size_t)head * LSEQ * DIM;
    const float* Kg = K + hoff + (size_t)(kb * KBLK) * DIM;
    const float* Vg = V + hoff + (size_t)(kb * KBLK) * DIM;
    u16* outK = wsK + (size_t)b * 4096;
    u16* outV = wsV + (size_t)b * 4096;

    // stage V tile fp32 into LDS (coalesced read), [k][d] pitch 65
#pragma unroll
    for (int i = 0; i < 16; ++i) {
        const int e = t + 256 * i;
        sv[e >> 6][e & 63] = Vg[e];    // Vg is [k][d] contiguous: e = k*64+d
    }
    // K: 2 output chunks of 16B per thread (reads cover full rows, writes coalesced)
#pragma unroll
    for (int i = 0; i < 2; ++i) {
        const int c = t + 256 * i;
        const int r = c >> 3, q = c & 7;
        const int d0 = 8 * (q ^ (r & 7));
        float4 a  = *(const float4*)(Kg + r * DIM + d0);
        float4 bb = *(const float4*)(Kg + r * DIM + d0 + 4);
        union { u16 h[8]; uint4 u; } pk;
        pk.h[0]=f2bf(a.x);  pk.h[1]=f2bf(a.y);  pk.h[2]=f2bf(a.z);  pk.h[3]=f2bf(a.w);
        pk.h[4]=f2bf(bb.x); pk.h[5]=f2bf(bb.y); pk.h[6]=f2bf(bb.z); pk.h[7]=f2bf(bb.w);
        *(uint4*)(outK + c * 8) = pk.u;
    }
    __syncthreads();
    // V^T: 2 output chunks per thread, gathered from LDS
#pragma unroll
    for (int i = 0; i < 2; ++i) {
        const int c = t + 256 * i;
        const int d = c >> 3, q = c & 7;
        const int cl = q ^ (d & 7);
        const int mp = cl >> 2, lq = cl & 3;
        union { u16 h[8]; uint4 u; } pk;
#pragma unroll
        for (int s = 0; s < 2; ++s) {
            const int k0 = 4 * (8 * mp + 4 * s + lq);
#pragma unroll
            for (int j = 0; j < 4; ++j)
                pk.h[4 * s + j] = f2bf(sv[k0 + j][d]);
        }
        *(uint4*)(outV + c * 8) = pk.u;
    }
}

// ============================================================================
// Main fused kernel: zero staging work in-loop (gload_lds direct), one
// vmcnt(0)+s_barrier per tile, swizzled min-conflict ds_read_b128 fragments.
// ============================================================================
__launch_bounds__(256, 4)
__global__ void attn_fused_kernel(const float* __restrict__ Q,
                                  const u16* __restrict__ wsK,
                                  const u16* __restrict__ wsV,
                                  const float* __restrict__ Msk,
                                  float* __restrict__ out,
                                  float* __restrict__ loss)
{
    __shared__ __align__(16) u16 lds_k[2][4096];   // 8KB K tile image x2
    __shared__ __align__(16) u16 lds_v[2][4096];   // 8KB V^T tile image x2

    const int t  = threadIdx.x;
    // bijective XCD-chunked swizzle: 1024 blocks, 8 XCDs, 128-block chunks
    const int wg   = ((int)blockIdx.x & 7) * 128 + ((int)blockIdx.x >> 3);
    const int head = wg >> 5;
    const int qb   = wg & 31;
    const int qbase = qb * QBLK;
    const int w  = t >> 6;
    const int l  = t & 63;
    const int lr = l & 15;
    const int lq = l >> 4;
    const int x7 = lr & 7;

    const size_t hoff = (size_t)head * LSEQ * DIM;
    const int qg = qbase + 16 * w + lr;

    // ---- Q fragments, scale folded in (slots c = 32s + 8lq + j) ----
    bf16x8 qf[2];
#pragma unroll
    for (int s = 0; s < 2; ++s) {
        const float* src = Q + hoff + (size_t)qg * DIM + 32 * s + 8 * lq;
        float4 a = *(const float4*)(src);
        float4 b = *(const float4*)(src + 4);
        union { u16 h[8]; bf16x8 v; } u;
        u.h[0] = f2bf(a.x * QSCALE); u.h[1] = f2bf(a.y * QSCALE);
        u.h[2] = f2bf(a.z * QSCALE); u.h[3] = f2bf(a.w * QSCALE);
        u.h[4] = f2bf(b.x * QSCALE); u.h[5] = f2bf(b.y * QSCALE);
        u.h[6] = f2bf(b.z * QSCALE); u.h[7] = f2bf(b.w * QSCALE);
        qf[s] = u.v;
    }

    f32x4 acc[4];
#pragma unroll
    for (int dt = 0; dt < 4; ++dt) acc[dt] = (f32x4){0.f, 0.f, 0.f, 0.f};
    float mrun = -1e30f, lrun = 0.f, la2 = 0.f, lam = 0.f;

    const u16* srcK = wsK + (size_t)(head * NTILE) * 4096 + t * 8;
    const u16* srcV = wsV + (size_t)(head * NTILE) * 4096 + t * 8;

    auto stage = [&](int buf, int kb) {
        const u16* gk = srcK + (size_t)kb * 4096;
        const u16* gv = srcV + (size_t)kb * 4096;
        gl_lds16(gk,        &lds_k[buf][t * 8]);
        gl_lds16(gk + 2048, &lds_k[buf][t * 8 + 2048]);
        gl_lds16(gv,        &lds_v[buf][t * 8]);
        gl_lds16(gv + 2048, &lds_v[buf][t * 8 + 2048]);
    };

    stage(0, 0);
    int cur = 0;

    for (int kb = 0; kb < NTILE; ++kb) {
        TILE_SYNC();   // own stages drained; all waves' stages drained + synced

        // ---- mask straight to registers (older than stage-next in vmcnt order) ----
        f32x4 mreg[4];
        {
            const float* mp_ = Msk + (size_t)qg * LSEQ + kb * KBLK + 4 * lq;
#pragma unroll
            for (int m = 0; m < 4; ++m)
                mreg[m] = *(const f32x4*)(mp_ + 16 * m);
        }

        if (kb + 1 < NTILE) stage(cur ^ 1, kb + 1);   // flies across whole tile body

        // ---- S^T = K * Q^T : D col=q(=lr), row k = 16m + 4lq + r ----
        f32x4 S[4];
        __builtin_amdgcn_s_setprio(1);
#pragma unroll
        for (int m = 0; m < 4; ++m) {
            const u16* kro = &lds_k[cur][(16 * m + lr) * 64];
            bf16x8 kf0 = *(const bf16x8*)(kro + ((lq ^ x7) << 3));
            bf16x8 kf1 = *(const bf16x8*)(kro + (((lq + 4) ^ x7) << 3));
            f32x4 z = (f32x4){0.f, 0.f, 0.f, 0.f};
            z = __builtin_amdgcn_mfma_f32_16x16x32_bf16(kf0, qf[0], z, 0, 0, 0);
            z = __builtin_amdgcn_mfma_f32_16x16x32_bf16(kf1, qf[1], z, 0, 0, 0);
            S[m] = z;
        }
        __builtin_amdgcn_s_setprio(0);

        // ---- in-lane online softmax with defer-max ----
        float tm = fmaxf(fmaxf(fmaxf(S[0][0], S[0][1]), fmaxf(S[0][2], S[0][3])),
                         fmaxf(fmaxf(S[1][0], S[1][1]), fmaxf(S[1][2], S[1][3])));
        tm = fmaxf(tm, fmaxf(fmaxf(fmaxf(S[2][0], S[2][1]), fmaxf(S[2][2], S[2][3])),
                             fmaxf(fmaxf(S[3][0], S[3][1]), fmaxf(S[3][2], S[3][3]))));
        tm = fmaxf(tm, __shfl_xor(tm, 16));
        tm = fmaxf(tm, __shfl_xor(tm, 32));
        if (!__all(tm - mrun <= RESCALE_THR)) {      // wave-uniform branch
            const float mn = fmaxf(mrun, tm);
            const float al = __builtin_amdgcn_exp2f(mrun - mn);
            mrun = mn;
            lrun *= al; la2 *= al * al; lam *= al;
#pragma unroll
            for (int dt = 0; dt < 4; ++dt) acc[dt] *= al;
        }

        float psum = 0.f, pp2 = 0.f, ppm = 0.f;
        u16 pb[16];
#pragma unroll
        for (int m = 0; m < 4; ++m) {
#pragma unroll
            for (int r = 0; r < 4; ++r) {
                float p = __builtin_amdgcn_exp2f(S[m][r] - mrun);
                psum += p;
                pp2  += p * p;
                ppm  += p * mreg[m][r];
                pb[4 * m + r] = f2bf(p);
            }
        }
        lrun += psum; la2 += pp2; lam += ppm;

        // ---- O^T += V^T * P ----
        bf16x8 pf[2];
#pragma unroll
        for (int mp = 0; mp < 2; ++mp) {
            union { u16 h[8]; bf16x8 v; } u;
#pragma unroll
            for (int j = 0; j < 4; ++j) { u.h[j] = pb[8 * mp + j]; u.h[4 + j] = pb[8 * mp + 4 + j]; }
            pf[mp] = u.v;
        }
        __builtin_amdgcn_s_setprio(1);
#pragma unroll
        for (int dt = 0; dt < 4; ++dt) {
            const u16* vro = &lds_v[cur][(16 * dt + lr) * 64];
#pragma unroll
            for (int mp = 0; mp < 2; ++mp) {
                bf16x8 vf = *(const bf16x8*)(vro + (((4 * mp + lq) ^ x7) << 3));
                acc[dt] = __builtin_amdgcn_mfma_f32_16x16x32_bf16(vf, pf[mp], acc[dt], 0, 0, 0);
            }
        }
        __builtin_amdgcn_s_setprio(0);
        cur ^= 1;
    }

    // ---- reduce per-lane partials across the 4 k-groups ----
#pragma unroll
    for (int off = 16; off <= 32; off <<= 1) {
        lrun += __shfl_xor(lrun, off);
        la2  += __shfl_xor(la2,  off);
        lam  += __shfl_xor(lam,  off);
    }

    const float inv = 1.0f / lrun;

#pragma unroll
    for (int dt = 0; dt < 4; ++dt) {
        float4 o;
        o.x = acc[dt][0] * inv; o.y = acc[dt][1] * inv;
        o.z = acc[dt][2] * inv; o.w = acc[dt][3] * inv;
        *(float4*)(out + hoff + (size_t)qg * DIM + 16 * dt + 4 * lq) = o;
    }

    float part = la2 * inv * inv - 2.0f * lam * inv;
    part = (l < 16) ? part : 0.f;
#pragma unroll
    for (int off = 1; off <= 8; off <<= 1) part += __shfl_xor(part, off);
    if (l == 0) atomicAdd(loss, part);
}

// ============================================================================
// Fallback (proven r3 kernel, 147 us) if workspace is too small.
// ============================================================================
__launch_bounds__(256, 4)
__global__ void attn_fallback_kernel(const float* __restrict__ Q,
                                     const float* __restrict__ K,
                                     const float* __restrict__ V,
                                     const float* __restrict__ Msk,
                                     float* __restrict__ out,
                                     float* __restrict__ loss)
{
    __shared__ __align__(16) u16 lds_k[64][72];
    __shared__ __align__(16) u16 lds_v[64][68];

    const int t  = threadIdx.x;
    const int wg   = ((int)blockIdx.x & 7) * 128 + ((int)blockIdx.x >> 3);
    const int head = wg >> 5;
    const int qb   = wg & 31;
    const int qbase = qb * QBLK;
    const int w  = t >> 6;
    const int l  = t & 63;
    const int lr = l & 15;
    const int lq = l >> 4;

    const size_t hoff = (size_t)head * LSEQ * DIM;
    const int qg = qbase + 16 * w + lr;

    bf16x8 qf[2];
#pragma unroll
    for (int s = 0; s < 2; ++s) {
        const float* src = Q + hoff + (size_t)qg * DIM + 32 * s + 8 * lq;
        float4 a = *(const float4*)(src);
        float4 b = *(const float4*)(src + 4);
        union { u16 h[8]; bf16x8 v; } u;
        u.h[0] = f2bf(a.x * QSCALE); u.h[1] = f2bf(a.y * QSCALE);
        u.h[2] = f2bf(a.z * QSCALE); u.h[3] = f2bf(a.w * QSCALE);
        u.h[4] = f2bf(b.x * QSCALE); u.h[5] = f2bf(b.y * QSCALE);
        u.h[6] = f2bf(b.z * QSCALE); u.h[7] = f2bf(b.w * QSCALE);
        qf[s] = u.v;
    }

    f32x4 acc[4];
#pragma unroll
    for (int dt = 0; dt < 4; ++dt) acc[dt] = (f32x4){0.f, 0.f, 0.f, 0.f};
    float mrun = -1e30f, lrun = 0.f, la2 = 0.f, lam = 0.f;

    for (int kb = 0; kb < NTILE; ++kb) {
        const int kbase = kb * KBLK;
        __syncthreads();
        f32x4 mreg[4];
        {
            const float* mp_ = Msk + (size_t)qg * LSEQ + kbase + 4 * lq;
#pragma unroll
            for (int m = 0; m < 4; ++m)
                mreg[m] = *(const f32x4*)(mp_ + 16 * m);
        }
        {
            const float* Kg = K + hoff + (size_t)kbase * DIM;
            const float* Vg = V + hoff + (size_t)kbase * DIM;
#pragma unroll
            for (int i = 0; i < 4; ++i) {
                const int id = t + 256 * i;
                const int r = id >> 4, c = (id & 15) * 4;
                float4 kv = *(const float4*)(Kg + r * DIM + c);
                float4 vv = *(const float4*)(Vg + r * DIM + c);
                st4bf(&lds_k[r][c], kv);
                lds_v[c + 0][r] = f2bf(vv.x);
                lds_v[c + 1][r] = f2bf(vv.y);
                lds_v[c + 2][r] = f2bf(vv.z);
                lds_v[c + 3][r] = f2bf(vv.w);
            }
        }
        __syncthreads();

        f32x4 S[4];
#pragma unroll
        for (int m = 0; m < 4; ++m) {
            bf16x8 kf0 = *(const bf16x8*)&lds_k[16 * m + lr][8 * lq];
            bf16x8 kf1 = *(const bf16x8*)&lds_k[16 * m + lr][32 + 8 * lq];
            f32x4 z = (f32x4){0.f, 0.f, 0.f, 0.f};
            z = __builtin_amdgcn_mfma_f32_16x16x32_bf16(kf0, qf[0], z, 0, 0, 0);
            z = __builtin_amdgcn_mfma_f32_16x16x32_bf16(kf1, qf[1], z, 0, 0, 0);
            S[m] = z;
        }

        float tm = fmaxf(fmaxf(fmaxf(S[0][0], S[0][1]), fmaxf(S[0][2], S[0][3])),
                         fmaxf(fmaxf(S[1][0], S[1][1]), fmaxf(S[1][2], S[1][3])));
        tm = fmaxf(tm, fmaxf(fmaxf(fmaxf(S[2][0], S[2][1]), fmaxf(S[2][2], S[2][3])),
                             fmaxf(fmaxf(S[3][0], S[3][1]), fmaxf(S[3][2], S[3][3]))));
        tm = fmaxf(tm, __shfl_xor(tm, 16));
        tm = fmaxf(tm, __shfl_xor(tm, 32));
        if (!__all(tm - mrun <= RESCALE_THR)) {
            const float mn = fmaxf(mrun, tm);
            const float al = __builtin_amdgcn_exp2f(mrun - mn);
            mrun = mn;
            lrun *= al; la2 *= al * al; lam *= al;
#pragma unroll
            for (int dt = 0; dt < 4; ++dt) acc[dt] *= al;
        }

        float psum = 0.f, pp2 = 0.f, ppm = 0.f;
        u16 pb[16];
#pragma unroll
        for (int m = 0; m < 4; ++m) {
#pragma unroll
            for (int r = 0; r < 4; ++r) {
                float p = __builtin_amdgcn_exp2f(S[m][r] - mrun);
                psum += p;
                pp2  += p * p;
                ppm  += p * mreg[m][r];
                pb[4 * m + r] = f2bf(p);
            }
        }
        lrun += psum; la2 += pp2; lam += ppm;

        bf16x8 pf[2];
#pragma unroll
        for (int mp = 0; mp < 2; ++mp) {
            union { u16 h[8]; bf16x8 v; } u;
#pragma unroll
            for (int j = 0; j < 4; ++j) { u.h[j] = pb[8 * mp + j]; u.h[4 + j] = pb[8 * mp + 4 + j]; }
            pf[mp] = u.v;
        }
#pragma unroll
        for (int dt = 0; dt < 4; ++dt) {
#pragma unroll
            for (int mp = 0; mp < 2; ++mp) {
                bf16x8 vf = comb64(&lds_v[16 * dt + lr][32 * mp + 4 * lq],
                                   &lds_v[16 * dt + lr][32 * mp + 16 + 4 * lq]);
                acc[dt] = __builtin_amdgcn_mfma_f32_16x16x32_bf16(vf, pf[mp], acc[dt], 0, 0, 0);
            }
        }
    }

#pragma unroll
    for (int off = 16; off <= 32; off <<= 1) {
        lrun += __shfl_xor(lrun, off);
        la2  += __shfl_xor(la2,  off);
        lam  += __shfl_xor(lam,  off);
    }
    const float inv = 1.0f / lrun;
#pragma unroll
    for (int dt = 0; dt < 4; ++dt) {
        float4 o;
        o.x = acc[dt][0] * inv; o.y = acc[dt][1] * inv;
        o.z = acc[dt][2] * inv; o.w = acc[dt][3] * inv;
        *(float4*)(out + hoff + (size_t)qg * DIM + 16 * dt + 4 * lq) = o;
    }
    float part = la2 * inv * inv - 2.0f * lam * inv;
    part = (l < 16) ? part : 0.f;
#pragma unroll
    for (int off = 1; off <= 8; off <<= 1) part += __shfl_xor(part, off);
    if (l == 0) atomicAdd(loss, part);
}

// loss += 32 * sum(mask^2), fp32
__global__ void masksq_kernel(const float* __restrict__ Msk, float* __restrict__ loss)
{
    __shared__ float red[4];
    float s = 0.f;
    const size_t n4 = (size_t)LSEQ * LSEQ / 4;
    for (size_t i = (size_t)blockIdx.x * blockDim.x + threadIdx.x; i < n4;
         i += (size_t)gridDim.x * blockDim.x) {
        float4 v = ((const float4*)Msk)[i];
        s += v.x * v.x + v.y * v.y + v.z * v.z + v.w * v.w;
    }
#pragma unroll
    for (int off = 1; off <= 32; off <<= 1) s += __shfl_xor(s, off);
    if ((threadIdx.x & 63) == 0) red[threadIdx.x >> 6] = s;
    __syncthreads();
    if (threadIdx.x == 0) {
        float tot = red[0] + red[1] + red[2] + red[3];
        atomicAdd(loss, 32.0f * tot);
    }
}

extern "C" void kernel_launch(void* const* d_in, const int* in_sizes, int n_in,
                              void* d_out, int out_size, void* d_ws, size_t ws_size,
                              hipStream_t stream)
{
    const float* Q   = (const float*)d_in[0];
    const float* K   = (const float*)d_in[1];
    const float* V   = (const float*)d_in[2];
    const float* Msk = (const float*)d_in[3];
    float* out  = (float*)d_out;
    float* loss = out + (size_t)NHEAD * LSEQ * DIM;  // element 4194304

    hipMemsetAsync(loss, 0, sizeof(float), stream);
    masksq_kernel<<<256, 256, 0, stream>>>(Msk, loss);

    const size_t need = (size_t)2 * NHEAD * NTILE * 4096 * sizeof(u16);  // 16 MB
    if (d_ws && ws_size >= need) {
        u16* wsK = (u16*)d_ws;
        u16* wsV = wsK + (size_t)NHEAD * NTILE * 4096;
        prepack_kernel<<<NHEAD * NTILE, 256, 0, stream>>>(K, V, wsK, wsV);
        attn_fused_kernel<<<NHEAD * (LSEQ / QBLK), 256, 0, stream>>>(Q, wsK, wsV, Msk, out, loss);
    } else {
        attn_fallback_kernel<<<NHEAD * (LSEQ / QBLK), 256, 0, stream>>>(Q, K, V, Msk, out, loss);
    }
}